// Round 1
// baseline (66.794 us; speedup 1.0000x reference)
//
#include <hip/hip_runtime.h>

#define NB   384          // batch
#define ND   256          // embedding dim
#define NTHR 192          // 3 waves
#define HB   0x80808080u  // byte-MSB mask
#define KMUL 0x00204081u  // gathers bits {7,15,23,31} -> {28..31}
#define EPSF 1e-6f

// One block per (i, k-half). Thread owns k = khalf*192+tid; loops over j.
// total += relu(d_ij - d_ik + margin) * Wlut[taskbits(i,j,k)]
// where Wlut folds task_weight/count (count computed analytically from a
// ranking histogram), so a single scalar accumulator suffices.
__global__ __launch_bounds__(NTHR) void mtrl_kernel(
    const float* __restrict__ emb,
    const float* __restrict__ tw,
    const int*   __restrict__ rank,
    float* __restrict__ out)
{
    __shared__ float4   dp[NB];     // {d_ij + margin, H - rp_j, gt[i,j] bits, 0}
    __shared__ float    ei[ND];     // embedding row i
    __shared__ float    wlut[16];   // sum of w_t/count_t over set task bits
    __shared__ unsigned hist[20];   // 4 tasks x 5 rank values
    __shared__ double   wp[4];
    __shared__ float    red[3];

    const int tid   = threadIdx.x;
    const int bi    = blockIdx.x >> 1;
    const int khalf = blockIdx.x & 1;

    if (tid < 20) hist[tid] = 0u;
    if (tid < ND / 4)
        reinterpret_cast<float4*>(ei)[tid] =
            reinterpret_cast<const float4*>(emb + (size_t)bi * ND)[tid];
    __syncthreads();

    // ranking histogram (shared atomics; ~8 adds/thread, low contention)
    for (int e = tid; e < NB * 4; e += NTHR)
        atomicAdd(&hist[(e & 3) * 5 + rank[e]], 1u);

    // packed ranks of row i (uniform -> scalar loads)
    const int* ri = rank + bi * 4;
    const unsigned rpi = (unsigned)ri[0] | ((unsigned)ri[1] << 8) |
                         ((unsigned)ri[2] << 16) | ((unsigned)ri[3] << 24);
    const unsigned hmi = HB - rpi;  // per-byte 128 - r_i (no borrows, r<=4)

    // distance row i (+margin) and per-j packed helpers
    for (int j = tid; j < NB; j += NTHR) {
        const float4* ej4 = reinterpret_cast<const float4*>(emb + (size_t)j * ND);
        const float4* ei4 = reinterpret_cast<const float4*>(ei);
        float s = 0.f;
        #pragma unroll 8
        for (int d = 0; d < ND / 4; ++d) {
            float4 a = ei4[d];
            float4 b = ej4[d];
            float dx = a.x - b.x + EPSF;
            float dy = a.y - b.y + EPSF;
            float dz = a.z - b.z + EPSF;
            float dw = a.w - b.w + EPSF;
            s = fmaf(dx, dx, s);
            s = fmaf(dy, dy, s);
            s = fmaf(dz, dz, s);
            s = fmaf(dw, dw, s);
        }
        const int4 rj4 = *reinterpret_cast<const int4*>(rank + j * 4);
        const unsigned rpj = (unsigned)rj4.x | ((unsigned)rj4.y << 8) |
                             ((unsigned)rj4.z << 16) | ((unsigned)rj4.w << 24);
        // byte b of (rpj + 128 - rpi) has MSB==0  <=>  r_i > r_j
        const unsigned mij = ~(rpj + hmi) & HB;   // gt[i,j] bits at 7/15/23/31
        const unsigned hj  = HB - rpj;
        float4 v;
        v.x = sqrtf(s) + 1.0f;                    // d_ij + MARGIN
        v.y = __uint_as_float(hj);
        v.z = __uint_as_float(mij);
        v.w = 0.f;
        dp[j] = v;
    }
    __syncthreads();

    // analytic counts: count_t = sum_v hist[v] * below(v) * above(v)
    if (tid < 4) {
        double c = 0.0;
        unsigned below = 0;
        #pragma unroll
        for (int v = 0; v < 5; ++v) {
            unsigned hv = hist[tid * 5 + v];
            unsigned above = (unsigned)NB - below - hv;
            c += (double)hv * (double)below * (double)above;
            below += hv;
        }
        wp[tid] = (c > 0.0) ? (double)tw[tid] / c : 0.0;  // count>0 gate folded in
    }
    __syncthreads();
    if (tid < 16) {
        double w = 0.0;
        if (tid & 1) w += wp[0];
        if (tid & 2) w += wp[1];
        if (tid & 4) w += wp[2];
        if (tid & 8) w += wp[3];
        wlut[tid] = (float)w;                    // wlut[0] == 0 absorbs masked triples
    }
    __syncthreads();

    // heavy phase: thread owns k, iterate all j (branchless, identical per block)
    const int k = khalf * NTHR + tid;
    const float dik = dp[k].x - 1.0f;            // raw d_ik
    const int4 rk4 = *reinterpret_cast<const int4*>(rank + k * 4);
    const unsigned rpk = (unsigned)rk4.x | ((unsigned)rk4.y << 8) |
                         ((unsigned)rk4.z << 16) | ((unsigned)rk4.w << 24);

    float tsum = 0.f;
    #pragma unroll 4
    for (int j = 0; j < NB; ++j) {
        float4 d4 = dp[j];                                  // broadcast ds_read_b128
        const unsigned hj  = __float_as_uint(d4.y);
        const unsigned mij = __float_as_uint(d4.z);
        // byte MSB of (rpk + 128 - rpj) == 0  <=>  r_j > r_k
        const unsigned bits = ((rpk + hj) ^ HB) & mij;      // gt[i,j] & gt[j,k]
        const unsigned idx  = (bits * KMUL) >> 28;          // 4-bit task index
        const float v = fmaxf(d4.x - dik, 0.f);             // relu(d_ij - d_ik + 1)
        tsum = fmaf(v, wlut[idx], tsum);
    }

    // block reduction: wave shuffle then cross-wave via LDS
    #pragma unroll
    for (int off = 32; off > 0; off >>= 1)
        tsum += __shfl_down(tsum, off);
    if ((tid & 63) == 0) red[tid >> 6] = tsum;
    __syncthreads();
    if (tid == 0)
        atomicAdd(out, red[0] + red[1] + red[2]);
}

extern "C" void kernel_launch(void* const* d_in, const int* in_sizes, int n_in,
                              void* d_out, int out_size, void* d_ws, size_t ws_size,
                              hipStream_t stream)
{
    (void)in_sizes; (void)n_in; (void)out_size; (void)d_ws; (void)ws_size;
    const float* emb  = (const float*)d_in[0];
    const float* tw   = (const float*)d_in[1];
    const int*   rank = (const int*)d_in[2];
    float* out = (float*)d_out;

    hipMemsetAsync(out, 0, sizeof(float), stream);
    mtrl_kernel<<<NB * 2, NTHR, 0, stream>>>(emb, tw, rank, out);
}